// Round 1
// baseline (807.254 us; speedup 1.0000x reference)
//
#include <hip/hip_runtime.h>

#define F_IN 512
#define HDIM 16
#define F_OUT 40

__device__ __forceinline__ int load_idx(const void* ei, int is64, long long i) {
  if (is64) return (int)((const long long*)ei)[i];
  return ((const int*)ei)[i];
}

extern "C" __global__ void k_init(int* __restrict__ cnt, int n, int* __restrict__ flag) {
  int i = blockIdx.x * blockDim.x + threadIdx.x;
  if (i < n) cnt[i] = 0;
  if (i == 0) *flag = 1;
}

// If edge_index is int64, every odd 32-bit word (high half) of the first
// npairs values is 0. If int32, those words are random node ids (almost all
// nonzero). flag stays 1 => treat as int64.
extern "C" __global__ void k_detect(const unsigned int* __restrict__ w, int npairs,
                                    int* __restrict__ flag) {
  int i = blockIdx.x * blockDim.x + threadIdx.x;
  if (i < npairs && w[2 * i + 1] != 0u) atomicAnd(flag, 0);
}

extern "C" __global__ void k_deg(const void* __restrict__ ei, int E, int* __restrict__ cnt,
                                 const int* __restrict__ flag) {
  int e = blockIdx.x * blockDim.x + threadIdx.x;
  if (e >= E) return;
  int is64 = *flag;
  int c = load_idx(ei, is64, (long long)E + e);  // targets = second row
  atomicAdd(&cnt[c], 1);
}

extern "C" __global__ void k_dis(const int* __restrict__ cnt, float* __restrict__ dis, int n) {
  int i = blockIdx.x * blockDim.x + threadIdx.x;
  if (i < n) dis[i] = rsqrtf((float)cnt[i] + 1.0f);  // +1 self loop; deg>=1 always
}

extern "C" __global__ void k_scan1(const int* __restrict__ cnt, int* __restrict__ offs,
                                   int* __restrict__ bsum, int n) {
  __shared__ int sh[256];
  int tid = threadIdx.x;
  int i = blockIdx.x * 256 + tid;
  int v = (i < n) ? cnt[i] : 0;
  sh[tid] = v;
  __syncthreads();
  for (int d = 1; d < 256; d <<= 1) {
    int t = (tid >= d) ? sh[tid - d] : 0;
    __syncthreads();
    sh[tid] += t;
    __syncthreads();
  }
  if (i < n) offs[i] = sh[tid] - v;           // block-local exclusive
  if (tid == 255) bsum[blockIdx.x] = sh[255]; // block total
}

extern "C" __global__ void k_scan2(int* __restrict__ bsum, int nb) {
  __shared__ int sh[512];
  int tid = threadIdx.x;
  int v = (tid < nb) ? bsum[tid] : 0;
  sh[tid] = v;
  __syncthreads();
  for (int d = 1; d < 512; d <<= 1) {
    int t = (tid >= d) ? sh[tid - d] : 0;
    __syncthreads();
    sh[tid] += t;
    __syncthreads();
  }
  if (tid < nb) bsum[tid] = sh[tid] - v;  // exclusive scan of block totals
}

extern "C" __global__ void k_scan3(int* __restrict__ offs, int* __restrict__ cur,
                                   const int* __restrict__ bsum, int n) {
  int i = blockIdx.x * blockDim.x + threadIdx.x;
  if (i < n) {
    int o = offs[i] + bsum[i >> 8];
    offs[i] = o;
    cur[i] = o;
  }
}

extern "C" __global__ void k_scatter(const void* __restrict__ ei, int E, int* __restrict__ cur,
                                     int* __restrict__ srcbuf, const int* __restrict__ flag) {
  int e = blockIdx.x * blockDim.x + threadIdx.x;
  if (e >= E) return;
  int is64 = *flag;
  int r = load_idx(ei, is64, e);
  int c = load_idx(ei, is64, (long long)E + e);
  int p = atomicAdd(&cur[c], 1);
  srcbuf[p] = r;
}

// h1 = x @ W1 : [n,512] @ [512,16]. One row per thread; W loads are
// wave-uniform (compiler should scalarize to s_load).
extern "C" __global__ __launch_bounds__(256) void k_mm1(
    const float* __restrict__ x, const float* __restrict__ W1, float* __restrict__ h1, int n) {
  int r = blockIdx.x * 256 + threadIdx.x;
  if (r >= n) return;
  const float4* xr = (const float4*)(x + (long long)r * F_IN);
  float acc[HDIM];
#pragma unroll
  for (int j = 0; j < HDIM; j++) acc[j] = 0.f;
  for (int k4 = 0; k4 < F_IN / 4; k4++) {
    float4 xv = xr[k4];
    float xk[4] = {xv.x, xv.y, xv.z, xv.w};
#pragma unroll
    for (int kk = 0; kk < 4; kk++) {
      const float4* wr = (const float4*)(W1 + (long long)(4 * k4 + kk) * HDIM);
#pragma unroll
      for (int q = 0; q < HDIM / 4; q++) {
        float4 wv = wr[q];
        acc[4 * q + 0] = fmaf(xk[kk], wv.x, acc[4 * q + 0]);
        acc[4 * q + 1] = fmaf(xk[kk], wv.y, acc[4 * q + 1]);
        acc[4 * q + 2] = fmaf(xk[kk], wv.z, acc[4 * q + 2]);
        acc[4 * q + 3] = fmaf(xk[kk], wv.w, acc[4 * q + 3]);
      }
    }
  }
  float4* o = (float4*)(h1 + (long long)r * HDIM);
#pragma unroll
  for (int q = 0; q < HDIM / 4; q++)
    o[q] = make_float4(acc[4 * q], acc[4 * q + 1], acc[4 * q + 2], acc[4 * q + 3]);
}

// hout[i][j] = di*sum_{s in N(i)} dis[s]*hin[s][j] + di*di*hin[i][j] (+bias, relu)
// thread = (node, feature): 16 lanes per node, 4 nodes per wave.
extern "C" __global__ void k_agg(const float* __restrict__ hin, const int* __restrict__ offs,
                                 const int* __restrict__ cnt, const int* __restrict__ srcbuf,
                                 const float* __restrict__ dis, const float* __restrict__ bias,
                                 int do_relu, float* __restrict__ hout, int n) {
  int t = blockIdx.x * blockDim.x + threadIdx.x;
  int i = t >> 4, j = t & 15;
  if (i >= n) return;
  int beg = offs[i];
  int c = cnt[i];
  float di = dis[i];
  float acc = 0.f;
  for (int p = 0; p < c; p++) {
    int s = srcbuf[beg + p];
    acc = fmaf(dis[s], hin[(long long)s * HDIM + j], acc);
  }
  float v = di * acc + di * di * hin[(long long)i * HDIM + j];
  if (bias) v += bias[j];
  if (do_relu) v = fmaxf(v, 0.f);
  hout[(long long)i * HDIM + j] = v;
}

// out = a2 @ W2 + b2 : [n,16] @ [16,40]. One row per thread.
extern "C" __global__ __launch_bounds__(256) void k_mm2(
    const float* __restrict__ a2, const float* __restrict__ W2, const float* __restrict__ b2,
    float* __restrict__ out, int n) {
  int r = blockIdx.x * 256 + threadIdx.x;
  if (r >= n) return;
  float a[HDIM];
  const float4* ar = (const float4*)(a2 + (long long)r * HDIM);
#pragma unroll
  for (int q = 0; q < HDIM / 4; q++) {
    float4 v = ar[q];
    a[4 * q] = v.x; a[4 * q + 1] = v.y; a[4 * q + 2] = v.z; a[4 * q + 3] = v.w;
  }
  float acc[F_OUT];
#pragma unroll
  for (int j = 0; j < F_OUT; j++) acc[j] = b2[j];
#pragma unroll
  for (int k = 0; k < HDIM; k++) {
    float ak = a[k];
    const float4* wr = (const float4*)(W2 + k * F_OUT);
#pragma unroll
    for (int q = 0; q < F_OUT / 4; q++) {
      float4 wv = wr[q];
      acc[4 * q + 0] = fmaf(ak, wv.x, acc[4 * q + 0]);
      acc[4 * q + 1] = fmaf(ak, wv.y, acc[4 * q + 1]);
      acc[4 * q + 2] = fmaf(ak, wv.z, acc[4 * q + 2]);
      acc[4 * q + 3] = fmaf(ak, wv.w, acc[4 * q + 3]);
    }
  }
  float4* o = (float4*)(out + (long long)r * F_OUT);
#pragma unroll
  for (int q = 0; q < F_OUT / 4; q++)
    o[q] = make_float4(acc[4 * q], acc[4 * q + 1], acc[4 * q + 2], acc[4 * q + 3]);
}

extern "C" void kernel_launch(void* const* d_in, const int* in_sizes, int n_in,
                              void* d_out, int out_size, void* d_ws, size_t ws_size,
                              hipStream_t stream) {
  const float* x = (const float*)d_in[0];
  const void* ei = d_in[1];
  const float* W1 = (const float*)d_in[2];
  const float* b1 = (const float*)d_in[3];
  const float* W2 = (const float*)d_in[4];
  const float* b2 = (const float*)d_in[5];
  float* out = (float*)d_out;

  const int n = in_sizes[0] / F_IN;  // 100000
  const int E = in_sizes[1] / 2;     // 3200000

  char* w = (char*)d_ws;
  auto alloc = [&](size_t bytes) {
    char* p = w;
    w += (bytes + 255) & ~(size_t)255;
    return p;
  };
  int* cnt = (int*)alloc((size_t)n * 4);
  int* offs = (int*)alloc((size_t)n * 4);
  int* cur = (int*)alloc((size_t)n * 4);
  float* dis = (float*)alloc((size_t)n * 4);
  int* flag = (int*)alloc(4);
  int* bsum = (int*)alloc(512 * 4);
  int* srcb = (int*)alloc((size_t)E * 4);
  float* h1 = (float*)alloc((size_t)n * HDIM * 4);
  float* z = (float*)alloc((size_t)n * HDIM * 4);
  float* a2 = (float*)alloc((size_t)n * HDIM * 4);

  int nb = (n + 255) / 256;
  dim3 B(256);
  hipLaunchKernelGGL(k_init, dim3(nb), B, 0, stream, cnt, n, flag);
  int npairs = 4096;
  if (npairs > E) npairs = E;
  hipLaunchKernelGGL(k_detect, dim3((npairs + 255) / 256), B, 0, stream,
                     (const unsigned int*)ei, npairs, flag);
  hipLaunchKernelGGL(k_deg, dim3((E + 255) / 256), B, 0, stream, ei, E, cnt, flag);
  hipLaunchKernelGGL(k_dis, dim3(nb), B, 0, stream, cnt, dis, n);
  hipLaunchKernelGGL(k_scan1, dim3(nb), B, 0, stream, cnt, offs, bsum, n);
  hipLaunchKernelGGL(k_scan2, dim3(1), dim3(512), 0, stream, bsum, nb);
  hipLaunchKernelGGL(k_scan3, dim3(nb), B, 0, stream, offs, cur, bsum, n);
  hipLaunchKernelGGL(k_scatter, dim3((E + 255) / 256), B, 0, stream, ei, E, cur, srcb, flag);
  hipLaunchKernelGGL(k_mm1, dim3(nb), B, 0, stream, x, W1, h1, n);
  hipLaunchKernelGGL(k_agg, dim3((n * 16 + 255) / 256), B, 0, stream, h1, offs, cnt, srcb, dis,
                     b1, 1, z, n);
  hipLaunchKernelGGL(k_agg, dim3((n * 16 + 255) / 256), B, 0, stream, z, offs, cnt, srcb, dis,
                     (const float*)nullptr, 0, a2, n);
  hipLaunchKernelGGL(k_mm2, dim3(nb), B, 0, stream, a2, W2, b2, out, n);
}